// Round 14
// baseline (1029.782 us; speedup 1.0000x reference)
//
#include <hip/hip_runtime.h>
#include <hip/hip_bf16.h>
#include <math.h>

// Problem constants
constexpr int BB   = 8;
constexpr int NN   = 4096;
constexpr int MM   = 1024;
constexpr int KK   = 16;
constexpr int COUT = 128;
#define RSQ 0.09f

__device__ __forceinline__ float dist2_exact(float ax, float ay, float az,
                                             float bx, float by, float bz) {
    // (a-b)^2 summed, no fma contraction: match numpy mul-then-add semantics
    float dx = __fsub_rn(ax, bx);
    float dy = __fsub_rn(ay, by);
    float dz = __fsub_rn(az, bz);
    return __fadd_rn(__fadd_rn(__fmul_rn(dx, dx), __fmul_rn(dy, dy)), __fmul_rn(dz, dz));
}

template<int CTRL>
__device__ __forceinline__ unsigned dpp_mov_u(unsigned v) {
    return (unsigned)__builtin_amdgcn_update_dpp((int)v, (int)v, CTRL, 0xF, 0xF, false);
}
__device__ __forceinline__ float readlane_f(float v, int j) {
    return __int_as_float(__builtin_amdgcn_readlane(__float_as_int(v), j));
}
__device__ __forceinline__ unsigned umax2(unsigned a, unsigned b) { return a > b ? a : b; }
__device__ __forceinline__ unsigned umin2(unsigned a, unsigned b) { return a < b ? a : b; }

// ---------------------------------------------------------------------------
// Kernel 1: farthest point sampling. One block per cloud.
//
// r13 -> r14 (single variable): 256 -> 512 threads, 8 pts/lane, 8 key slots.
// The d-update's SIMD issue (16 pts x 9 VALU x 2cyc = 288 cyc at 1 wave/SIMD)
// sat fully inside the serial iteration cycle; halving points/lane halves it,
// and each wave reaches its slot store earlier. Poll widens to 8 slots.
// Tie-break exactness: point p = tid + k*512; lane ctz -> min-k = min-index;
// u32 min over lanes/slots -> global min achiever. Key packing unchanged.
// Everything else (relaxed tagged poll, SGPR reduce, zero VMEM in loop,
// LDS history + bulk pos_s writeback) frozen from r13.
// ---------------------------------------------------------------------------
__global__ __launch_bounds__(512, 1) void fps_kernel(const float* __restrict__ pos,
                                                     float* __restrict__ pos_s,
                                                     float* __restrict__ batch_s) {
    const int b    = blockIdx.x;
    const int tid  = threadIdx.x;
    const int lane = tid & 63;
    const int wave = tid >> 6;
    const float* pb = pos + (size_t)b * NN * 3;

    __shared__ float4 spos[NN];                       // 64 KB
    __shared__ int    shist[MM];                      // 4 KB selection history
    __shared__ unsigned long long slotK[2][8];        // packed keys, parity-buffered

    for (int i = tid; i < NN; i += 512)
        spos[i] = make_float4(pb[i * 3 + 0], pb[i * 3 + 1], pb[i * 3 + 2], 0.0f);
    for (int i = tid; i < MM; i += 512)
        batch_s[(size_t)b * MM + i] = (float)b;       // constant, written up front
    if (tid == 0) shist[0] = 0;
    if (tid < 16) slotK[tid >> 3][tid & 7] = 0ull;    // tag sentinel (m starts at 1)
    __syncthreads();

    // registers: 8 strided points per thread (p = tid + k*512)
    float px[8], py[8], pz[8], d[8];
    const float4 p0 = spos[0];
#pragma unroll
    for (int k = 0; k < 8; k++) {
        float4 pt = spos[tid + k * 512];
        px[k] = pt.x; py[k] = pt.y; pz[k] = pt.z;
        d[k] = dist2_exact(pt.x, pt.y, pt.z, p0.x, p0.y, p0.z);
    }
    // depth-3 max tree (value only; order-independent, exact)
    float bv;
    {
        float t1[4];
#pragma unroll
        for (int k = 0; k < 4; k++) t1[k] = fmaxf(d[2 * k], d[2 * k + 1]);
        bv = fmaxf(fmaxf(t1[0], t1[1]), fmaxf(t1[2], t1[3]));
    }

    for (int m = 1; m < MM; m++) {
        const int par = m & 1;
        const unsigned tagm = (unsigned)m;            // m in [1,1023], fits 10 bits

        const unsigned bvb = __float_as_uint(bv);     // monotone bits (d >= +0)

        // ---- wave value max: 4 within-row DPP steps -> row maxima ----
        unsigned rv = bvb;
        rv = umax2(rv, dpp_mov_u<0x111>(rv));   // row_shr:1
        rv = umax2(rv, dpp_mov_u<0x112>(rv));   // row_shr:2
        rv = umax2(rv, dpp_mov_u<0x114>(rv));   // row_shr:4
        rv = umax2(rv, dpp_mov_u<0x118>(rv));   // row_shr:8
        // row maxima in lanes 15/31/47/63 -> scalar combine (SGPR result)
        const unsigned r0 = (unsigned)__builtin_amdgcn_readlane((int)rv, 15);
        const unsigned r1 = (unsigned)__builtin_amdgcn_readlane((int)rv, 31);
        const unsigned r2 = (unsigned)__builtin_amdgcn_readlane((int)rv, 47);
        const unsigned r3 = (unsigned)__builtin_amdgcn_readlane((int)rv, 63);
        const unsigned vstar = umax2(umax2(r0, r1), umax2(r2, r3));  // uniform

        // ---- lane's min-index achiever of bv (overlaps the chain above) ----
        unsigned kmask = 0u;
#pragma unroll
        for (int k = 0; k < 8; k++)
            kmask |= (d[k] == bv) ? (1u << k) : 0u;   // bv is bit-exactly one of d[k]
        const unsigned bi = (unsigned)(tid + (__builtin_ctz(kmask) << 9)); // point idx

        // ---- wave min point-index among achievers of vstar ----
        unsigned cand = (bvb == vstar) ? bi : 0xFFFFFFFFu;
        cand = umin2(cand, dpp_mov_u<0x111>(cand));
        cand = umin2(cand, dpp_mov_u<0x112>(cand));
        cand = umin2(cand, dpp_mov_u<0x114>(cand));
        cand = umin2(cand, dpp_mov_u<0x118>(cand));
        const unsigned c0 = (unsigned)__builtin_amdgcn_readlane((int)cand, 15);
        const unsigned c1 = (unsigned)__builtin_amdgcn_readlane((int)cand, 31);
        const unsigned c2 = (unsigned)__builtin_amdgcn_readlane((int)cand, 47);
        const unsigned c3 = (unsigned)__builtin_amdgcn_readlane((int)cand, 63);
        const unsigned wcand = umin2(umin2(c0, c1), umin2(c2, c3));  // uniform

        if (lane == 0) {
            const unsigned long long key =
                ((unsigned long long)vstar << 32)
                | (unsigned long long)(((4095u - wcand) << 10) | tagm);
            __hip_atomic_store(&slotK[par][wave], key, __ATOMIC_RELAXED,
                               __HIP_MEMORY_SCOPE_WORKGROUP);
        }

        // ---- poll the 8 slots until all carry tag m (relaxed) ----
        unsigned long long k0, k1, k2, k3, k4, k5, k6, k7;
        for (;;) {
            k0 = __hip_atomic_load(&slotK[par][0], __ATOMIC_RELAXED, __HIP_MEMORY_SCOPE_WORKGROUP);
            k1 = __hip_atomic_load(&slotK[par][1], __ATOMIC_RELAXED, __HIP_MEMORY_SCOPE_WORKGROUP);
            k2 = __hip_atomic_load(&slotK[par][2], __ATOMIC_RELAXED, __HIP_MEMORY_SCOPE_WORKGROUP);
            k3 = __hip_atomic_load(&slotK[par][3], __ATOMIC_RELAXED, __HIP_MEMORY_SCOPE_WORKGROUP);
            k4 = __hip_atomic_load(&slotK[par][4], __ATOMIC_RELAXED, __HIP_MEMORY_SCOPE_WORKGROUP);
            k5 = __hip_atomic_load(&slotK[par][5], __ATOMIC_RELAXED, __HIP_MEMORY_SCOPE_WORKGROUP);
            k6 = __hip_atomic_load(&slotK[par][6], __ATOMIC_RELAXED, __HIP_MEMORY_SCOPE_WORKGROUP);
            k7 = __hip_atomic_load(&slotK[par][7], __ATOMIC_RELAXED, __HIP_MEMORY_SCOPE_WORKGROUP);
            bool ok = (((unsigned)k0 & 1023u) == tagm) & (((unsigned)k1 & 1023u) == tagm) &
                      (((unsigned)k2 & 1023u) == tagm) & (((unsigned)k3 & 1023u) == tagm) &
                      (((unsigned)k4 & 1023u) == tagm) & (((unsigned)k5 & 1023u) == tagm) &
                      (((unsigned)k6 & 1023u) == tagm) & (((unsigned)k7 & 1023u) == tagm);
            if (ok) break;
        }

        // ---- combine: u64 max (value desc, then index asc), unpack ----
        unsigned long long kA = (k0 > k1) ? k0 : k1;
        unsigned long long kB = (k2 > k3) ? k2 : k3;
        unsigned long long kC = (k4 > k5) ? k4 : k5;
        unsigned long long kD = (k6 > k7) ? k6 : k7;
        unsigned long long kE = (kA > kB) ? kA : kB;
        unsigned long long kF = (kC > kD) ? kC : kD;
        unsigned long long kk = (kE > kF) ? kE : kF;
        const int fi = 4095 - (int)(((unsigned)kk >> 10) & 4095u);

        if (tid == 0) shist[m] = fi;

        const float4 sp = spos[fi];           // one ds_read_b128, uniform
        if (m < MM - 1) {
#pragma unroll
            for (int k = 0; k < 8; k++) {
                float nd = dist2_exact(px[k], py[k], pz[k], sp.x, sp.y, sp.z);
                d[k] = fminf(d[k], nd);
            }
            float t1[4];
#pragma unroll
            for (int k = 0; k < 4; k++) t1[k] = fmaxf(d[2 * k], d[2 * k + 1]);
            bv = fmaxf(fmaxf(t1[0], t1[1]), fmaxf(t1[2], t1[3]));
        }
    }

    // ---- write pos_s once, in parallel ----
    __syncthreads();
    for (int i = tid; i < MM; i += 512) {
        float4 sp = spos[shist[i]];
        size_t o = (size_t)b * MM + i;
        pos_s[o * 3 + 0] = sp.x;
        pos_s[o * 3 + 1] = sp.y;
        pos_s[o * 3 + 2] = sp.z;
    }
}

// ---------------------------------------------------------------------------
// Kernel 2 (FUSED radius + MLP): one wave per query. (frozen from r12)
// ---------------------------------------------------------------------------
__global__ __launch_bounds__(256, 1) void radius_mlp_kernel(const float* __restrict__ x,
                                                            const float* __restrict__ pos,
                                                            const float* __restrict__ pos_s,
                                                            const float* __restrict__ W1,
                                                            const float* __restrict__ b1,
                                                            const float* __restrict__ W2,
                                                            const float* __restrict__ b2,
                                                            const float* __restrict__ W3,
                                                            const float* __restrict__ b3,
                                                            float* __restrict__ out) {
    __shared__ float sW2[64 * 64];     // 16 KB
    __shared__ float sW3[64 * 128];    // 32 KB
    __shared__ int   nslot[4][16];     // per-wave neighbor slots (wave-private)

    const int tid  = threadIdx.x;
    const int lane = tid & 63;
    const int wave = tid >> 6;

    // stage W2/W3 (float4 vectorized), once per 4 queries
    {
        const float4* s2 = (const float4*)W2;
        float4*       d2 = (float4*)sW2;
        for (int i = tid; i < 64 * 64 / 4; i += 256) d2[i] = s2[i];
        const float4* s3 = (const float4*)W3;
        float4*       d3 = (float4*)sW3;
        for (int i = tid; i < 64 * 128 / 4; i += 256) d3[i] = s3[i];
    }
    // per-lane weight registers (lane = channel)
    float w1c[6];
#pragma unroll
    for (int c = 0; c < 6; c++) w1c[c] = W1[c * 64 + lane];
    const float bb1  = b1[lane];
    const float bb2  = b2[lane];
    const float bb3a = b3[lane];
    const float bb3b = b3[64 + lane];
    __syncthreads();

    const int q = blockIdx.x * 4 + wave;
    const int b = q >> 10;                    // q / MM
    const float qx = pos_s[q * 3 + 0];
    const float qy = pos_s[q * 3 + 1];
    const float qz = pos_s[q * 3 + 2];

    // ---- radius scan: first-16 by index within RSQ (identical semantics) ----
    if (lane < 16) nslot[wave][lane] = 0;     // wave-private init (no barrier)
    const float* pb = pos + (size_t)b * NN * 3;
    int cnt = 0;
    for (int c = 0; c < NN / 64; c++) {
        int p = c * 64 + lane;
        float px = pb[p * 3 + 0], py = pb[p * 3 + 1], pz = pb[p * 3 + 2];
        float d2 = dist2_exact(qx, qy, qz, px, py, pz);
        bool val = (d2 <= RSQ);
        unsigned long long msk = __ballot(val);
        if (val) {
            int rank = __popcll(msk & ((1ull << lane) - 1ull));
            int slot = cnt + rank;
            if (slot < KK) nslot[wave][slot] = p;
        }
        cnt += __popcll(msk);
        if (cnt >= KK) break;
    }
    const int cnt16 = min(cnt, KK);

    // neighbor indices (wave-uniform LDS broadcast reads)
    const int4 n0 = *(const int4*)&nslot[wave][0];
    const int4 n1 = *(const int4*)&nslot[wave][4];
    const int4 n2 = *(const int4*)&nslot[wave][8];
    const int4 n3 = *(const int4*)&nslot[wave][12];
    const int nidx[16] = { n0.x, n0.y, n0.z, n0.w, n1.x, n1.y, n1.z, n1.w,
                           n2.x, n2.y, n2.z, n2.w, n3.x, n3.y, n3.z, n3.w };

    // ---- layer 1: h[e] in registers (lane = channel), validity mask ----
    float h[17];
    unsigned vmask = 1u << 16;                // self edge always valid
#pragma unroll
    for (int e = 0; e < 16; e++) {
        const int p = (e < cnt16) ? nidx[e] : 0;
        const int g = b * NN + p;
        if ((e < cnt16) && (g != q)) vmask |= (1u << e);
        const float f0 = x[(size_t)g * 3 + 0];
        const float f1 = x[(size_t)g * 3 + 1];
        const float f2 = x[(size_t)g * 3 + 2];
        const float f3 = pos[(size_t)g * 3 + 0] - qx;
        const float f4 = pos[(size_t)g * 3 + 1] - qy;
        const float f5 = pos[(size_t)g * 3 + 2] - qz;
        float t = bb1 + f0 * w1c[0] + f1 * w1c[1] + f2 * w1c[2]
                      + f3 * w1c[3] + f4 * w1c[4] + f5 * w1c[5];
        h[e] = fmaxf(t, 0.0f);
    }
    {   // added self-loop: source row q of x/pos (PyG numeric quirk)
        const int g = q;
        const float f0 = x[(size_t)g * 3 + 0];
        const float f1 = x[(size_t)g * 3 + 1];
        const float f2 = x[(size_t)g * 3 + 2];
        const float f3 = pos[(size_t)g * 3 + 0] - qx;
        const float f4 = pos[(size_t)g * 3 + 1] - qy;
        const float f5 = pos[(size_t)g * 3 + 2] - qz;
        float t = bb1 + f0 * w1c[0] + f1 * w1c[1] + f2 * w1c[2]
                      + f3 * w1c[3] + f4 * w1c[4] + f5 * w1c[5];
        h[16] = fmaxf(t, 0.0f);
    }

    // ---- layer 2: readlane broadcast (VALU) + one ds W-read per j ----
    float acc[17];
#pragma unroll
    for (int e = 0; e < 17; e++) acc[e] = bb2;
#pragma unroll 2
    for (int j = 0; j < 64; j++) {
        const float wj = sW2[j * 64 + lane];
#pragma unroll
        for (int e = 0; e < 17; e++) {
            const float hj = readlane_f(h[e], j);
            acc[e] = __builtin_fmaf(hj, wj, acc[e]);
        }
    }
#pragma unroll
    for (int e = 0; e < 17; e++) h[e] = fmaxf(acc[e], 0.0f);

    // ---- layer 3: 2 channels/lane, readlane broadcast ----
    float a0[17], a1[17];
#pragma unroll
    for (int e = 0; e < 17; e++) { a0[e] = bb3a; a1[e] = bb3b; }
#pragma unroll 2
    for (int j = 0; j < 64; j++) {
        const float wa = sW3[j * 128 + lane];
        const float wb = sW3[j * 128 + 64 + lane];
#pragma unroll
        for (int e = 0; e < 17; e++) {
            const float hj = readlane_f(h[e], j);
            a0[e] = __builtin_fmaf(hj, wa, a0[e]);
            a1[e] = __builtin_fmaf(hj, wb, a1[e]);
        }
    }

    // ---- masked max over edges (order-insensitive) ----
    float m0 = -INFINITY, m1 = -INFINITY;
#pragma unroll
    for (int e = 0; e < 17; e++) {
        const bool v = (vmask >> e) & 1u;
        m0 = v ? fmaxf(m0, a0[e]) : m0;
        m1 = v ? fmaxf(m1, a1[e]) : m1;
    }
    out[(size_t)q * COUT + lane]      = m0;
    out[(size_t)q * COUT + 64 + lane] = m1;
}

// ---------------------------------------------------------------------------
extern "C" void kernel_launch(void* const* d_in, const int* in_sizes, int n_in,
                              void* d_out, int out_size, void* d_ws, size_t ws_size,
                              hipStream_t stream) {
    const float* x   = (const float*)d_in[0];
    const float* pos = (const float*)d_in[1];
    // d_in[2] = batch (unused: layout is implicit)
    const float* W1 = (const float*)d_in[3];
    const float* b1 = (const float*)d_in[4];
    const float* W2 = (const float*)d_in[5];
    const float* b2 = (const float*)d_in[6];
    const float* W3 = (const float*)d_in[7];
    const float* b3 = (const float*)d_in[8];

    float* outF    = (float*)d_out;
    float* out     = outF;                                  // [B*M, 128]
    float* pos_s   = outF + (size_t)BB * MM * COUT;         // [B*M, 3]
    float* batch_s = pos_s + (size_t)BB * MM * 3;           // [B*M]

    fps_kernel<<<BB, 512, 0, stream>>>(pos, pos_s, batch_s);
    radius_mlp_kernel<<<BB * MM / 4, 256, 0, stream>>>(x, pos, pos_s,
                                                       W1, b1, W2, b2, W3, b3, out);
}

// Round 15
// 952.962 us; speedup vs baseline: 1.0806x; 1.0806x over previous
//
#include <hip/hip_runtime.h>
#include <hip/hip_bf16.h>
#include <math.h>

// Problem constants
constexpr int BB   = 8;
constexpr int NN   = 4096;
constexpr int MM   = 1024;
constexpr int KK   = 16;
constexpr int COUT = 128;
#define RSQ 0.09f

typedef float v2f __attribute__((ext_vector_type(2)));

__device__ __forceinline__ float dist2_exact(float ax, float ay, float az,
                                             float bx, float by, float bz) {
    // (a-b)^2 summed, no fma contraction: match numpy mul-then-add semantics
    float dx = __fsub_rn(ax, bx);
    float dy = __fsub_rn(ay, by);
    float dz = __fsub_rn(az, bz);
    return __fadd_rn(__fadd_rn(__fmul_rn(dx, dx), __fmul_rn(dy, dy)), __fmul_rn(dz, dz));
}

// packed FP32 (VOP3P) helpers — IEEE-identical per component to the scalar
// ops (v_pk_add/mul are just two v_add/mul_f32 lanes); sub = add with exact
// negation modifier on src1. No fma contraction possible: asm is opaque.
__device__ __forceinline__ v2f pk_sub(v2f a, v2f b) {
    v2f r;
    asm("v_pk_add_f32 %0, %1, %2 neg_lo:[0,1] neg_hi:[0,1]"
        : "=v"(r) : "v"(a), "v"(b));
    return r;
}
__device__ __forceinline__ v2f pk_mul(v2f a, v2f b) {
    v2f r;
    asm("v_pk_mul_f32 %0, %1, %2" : "=v"(r) : "v"(a), "v"(b));
    return r;
}
__device__ __forceinline__ v2f pk_add(v2f a, v2f b) {
    v2f r;
    asm("v_pk_add_f32 %0, %1, %2" : "=v"(r) : "v"(a), "v"(b));
    return r;
}

template<int CTRL>
__device__ __forceinline__ unsigned dpp_mov_u(unsigned v) {
    return (unsigned)__builtin_amdgcn_update_dpp((int)v, (int)v, CTRL, 0xF, 0xF, false);
}
__device__ __forceinline__ float readlane_f(float v, int j) {
    return __int_as_float(__builtin_amdgcn_readlane(__float_as_int(v), j));
}
__device__ __forceinline__ unsigned umax2(unsigned a, unsigned b) { return a > b ? a : b; }
__device__ __forceinline__ unsigned umin2(unsigned a, unsigned b) { return a < b ? a : b; }

// ---------------------------------------------------------------------------
// Kernel 1: farthest point sampling. One block per cloud, 256 thr, 16 pts/lane
// (r14's 512-thread split REVERTED: per-SIMD issue is total-work-bound, so it
// only widened the reduce/poll -> +134us).
//
// r13 -> r15 (single variable on the r13 structure): the d-update uses packed
// FP32 (v_pk_mul/add, exact) -> 2 points per instruction; per-iteration SIMD
// issue for the update drops ~288 -> ~170 cyc. Pair k holds point indices
// tid+2k*256 (.x) and tid+(2k+1)*256 (.y); kmask bit order stays
// index-monotone so the jnp.argmax tie-break is unchanged. Everything else
// (SGPR reduce, relaxed tagged poll, zero VMEM in loop, bulk writeback)
// byte-identical to r13.
// ---------------------------------------------------------------------------
__global__ __launch_bounds__(256, 1) void fps_kernel(const float* __restrict__ pos,
                                                     float* __restrict__ pos_s,
                                                     float* __restrict__ batch_s) {
    const int b    = blockIdx.x;
    const int tid  = threadIdx.x;
    const int lane = tid & 63;
    const int wave = tid >> 6;
    const float* pb = pos + (size_t)b * NN * 3;

    __shared__ float4 spos[NN];                       // 64 KB
    __shared__ int    shist[MM];                      // 4 KB selection history
    __shared__ unsigned long long slotK[2][4];        // packed keys, parity-buffered

    for (int i = tid; i < NN; i += 256)
        spos[i] = make_float4(pb[i * 3 + 0], pb[i * 3 + 1], pb[i * 3 + 2], 0.0f);
    for (int i = tid; i < MM; i += 256)
        batch_s[(size_t)b * MM + i] = (float)b;       // constant, written up front
    if (tid == 0) shist[0] = 0;
    if (tid < 8) slotK[tid >> 2][tid & 3] = 0ull;     // tag sentinel (m starts at 1)
    __syncthreads();

    // registers: 16 strided points per thread as 8 float2 pairs
    // pair k: point (tid + 2k*256) in .x, point (tid + (2k+1)*256) in .y
    v2f pxv[8], pyv[8], pzv[8], dv[8];
    const float4 p0 = spos[0];
#pragma unroll
    for (int k = 0; k < 8; k++) {
        float4 ptA = spos[tid + (2 * k) * 256];
        float4 ptB = spos[tid + (2 * k + 1) * 256];
        pxv[k] = (v2f){ptA.x, ptB.x};
        pyv[k] = (v2f){ptA.y, ptB.y};
        pzv[k] = (v2f){ptA.z, ptB.z};
        dv[k].x = dist2_exact(ptA.x, ptA.y, ptA.z, p0.x, p0.y, p0.z);
        dv[k].y = dist2_exact(ptB.x, ptB.y, ptB.z, p0.x, p0.y, p0.z);
    }
    // depth-4 max tree (value only; order-independent, exact)
    float bv;
    {
        float t1[8], t2[4];
#pragma unroll
        for (int k = 0; k < 8; k++) t1[k] = fmaxf(dv[k].x, dv[k].y);
#pragma unroll
        for (int k = 0; k < 4; k++) t2[k] = fmaxf(t1[2 * k], t1[2 * k + 1]);
        bv = fmaxf(fmaxf(t2[0], t2[1]), fmaxf(t2[2], t2[3]));
    }

    for (int m = 1; m < MM; m++) {
        const int par = m & 1;
        const unsigned tagm = (unsigned)m;            // m in [1,1023], fits 10 bits

        const unsigned bvb = __float_as_uint(bv);     // monotone bits (d >= +0)

        // ---- wave value max: 4 within-row DPP steps -> row maxima ----
        unsigned rv = bvb;
        rv = umax2(rv, dpp_mov_u<0x111>(rv));   // row_shr:1
        rv = umax2(rv, dpp_mov_u<0x112>(rv));   // row_shr:2
        rv = umax2(rv, dpp_mov_u<0x114>(rv));   // row_shr:4
        rv = umax2(rv, dpp_mov_u<0x118>(rv));   // row_shr:8
        // row maxima in lanes 15/31/47/63 -> scalar combine (SGPR result)
        const unsigned r0 = (unsigned)__builtin_amdgcn_readlane((int)rv, 15);
        const unsigned r1 = (unsigned)__builtin_amdgcn_readlane((int)rv, 31);
        const unsigned r2 = (unsigned)__builtin_amdgcn_readlane((int)rv, 47);
        const unsigned r3 = (unsigned)__builtin_amdgcn_readlane((int)rv, 63);
        const unsigned vstar = umax2(umax2(r0, r1), umax2(r2, r3));  // uniform

        // ---- lane's min-index achiever of bv (overlaps the chain above) ----
        // bit (2k) = pair k .x, bit (2k+1) = pair k .y -> index-monotone
        unsigned kmask = 0u;
#pragma unroll
        for (int k = 0; k < 8; k++) {
            kmask |= (dv[k].x == bv) ? (1u << (2 * k)) : 0u;
            kmask |= (dv[k].y == bv) ? (1u << (2 * k + 1)) : 0u;
        }
        const unsigned bi = (unsigned)(tid + (__builtin_ctz(kmask) << 8)); // point idx

        // ---- wave min point-index among achievers of vstar ----
        unsigned cand = (bvb == vstar) ? bi : 0xFFFFFFFFu;
        cand = umin2(cand, dpp_mov_u<0x111>(cand));
        cand = umin2(cand, dpp_mov_u<0x112>(cand));
        cand = umin2(cand, dpp_mov_u<0x114>(cand));
        cand = umin2(cand, dpp_mov_u<0x118>(cand));
        const unsigned c0 = (unsigned)__builtin_amdgcn_readlane((int)cand, 15);
        const unsigned c1 = (unsigned)__builtin_amdgcn_readlane((int)cand, 31);
        const unsigned c2 = (unsigned)__builtin_amdgcn_readlane((int)cand, 47);
        const unsigned c3 = (unsigned)__builtin_amdgcn_readlane((int)cand, 63);
        const unsigned wcand = umin2(umin2(c0, c1), umin2(c2, c3));  // uniform

        if (lane == 0) {
            const unsigned long long key =
                ((unsigned long long)vstar << 32)
                | (unsigned long long)(((4095u - wcand) << 10) | tagm);
            __hip_atomic_store(&slotK[par][wave], key, __ATOMIC_RELAXED,
                               __HIP_MEMORY_SCOPE_WORKGROUP);
        }

        // ---- poll the 4 slots until all carry tag m (relaxed) ----
        unsigned long long k0, k1, k2, k3;
        for (;;) {
            k0 = __hip_atomic_load(&slotK[par][0], __ATOMIC_RELAXED, __HIP_MEMORY_SCOPE_WORKGROUP);
            k1 = __hip_atomic_load(&slotK[par][1], __ATOMIC_RELAXED, __HIP_MEMORY_SCOPE_WORKGROUP);
            k2 = __hip_atomic_load(&slotK[par][2], __ATOMIC_RELAXED, __HIP_MEMORY_SCOPE_WORKGROUP);
            k3 = __hip_atomic_load(&slotK[par][3], __ATOMIC_RELAXED, __HIP_MEMORY_SCOPE_WORKGROUP);
            bool ok = (((unsigned)k0 & 1023u) == tagm) &
                      (((unsigned)k1 & 1023u) == tagm) &
                      (((unsigned)k2 & 1023u) == tagm) &
                      (((unsigned)k3 & 1023u) == tagm);
            if (ok) break;
        }

        // ---- combine: u64 max (value desc, then index asc), unpack ----
        unsigned long long kA = (k0 > k1) ? k0 : k1;
        unsigned long long kB = (k2 > k3) ? k2 : k3;
        unsigned long long kk = (kA > kB) ? kA : kB;
        const int fi = 4095 - (int)(((unsigned)kk >> 10) & 4095u);

        if (tid == 0) shist[m] = fi;

        const float4 sp = spos[fi];           // one ds_read_b128, uniform
        if (m < MM - 1) {
            const v2f SX = (v2f){sp.x, sp.x};
            const v2f SY = (v2f){sp.y, sp.y};
            const v2f SZ = (v2f){sp.z, sp.z};
#pragma unroll
            for (int k = 0; k < 8; k++) {
                v2f dx = pk_sub(pxv[k], SX);
                v2f dy = pk_sub(pyv[k], SY);
                v2f dz = pk_sub(pzv[k], SZ);
                v2f s  = pk_add(pk_add(pk_mul(dx, dx), pk_mul(dy, dy)), pk_mul(dz, dz));
                dv[k].x = fminf(dv[k].x, s.x);
                dv[k].y = fminf(dv[k].y, s.y);
            }
            float t1[8], t2[4];
#pragma unroll
            for (int k = 0; k < 8; k++) t1[k] = fmaxf(dv[k].x, dv[k].y);
#pragma unroll
            for (int k = 0; k < 4; k++) t2[k] = fmaxf(t1[2 * k], t1[2 * k + 1]);
            bv = fmaxf(fmaxf(t2[0], t2[1]), fmaxf(t2[2], t2[3]));
        }
    }

    // ---- write pos_s once, in parallel ----
    __syncthreads();
    for (int i = tid; i < MM; i += 256) {
        float4 sp = spos[shist[i]];
        size_t o = (size_t)b * MM + i;
        pos_s[o * 3 + 0] = sp.x;
        pos_s[o * 3 + 1] = sp.y;
        pos_s[o * 3 + 2] = sp.z;
    }
}

// ---------------------------------------------------------------------------
// Kernel 2 (FUSED radius + MLP): one wave per query. (frozen from r12)
// ---------------------------------------------------------------------------
__global__ __launch_bounds__(256, 1) void radius_mlp_kernel(const float* __restrict__ x,
                                                            const float* __restrict__ pos,
                                                            const float* __restrict__ pos_s,
                                                            const float* __restrict__ W1,
                                                            const float* __restrict__ b1,
                                                            const float* __restrict__ W2,
                                                            const float* __restrict__ b2,
                                                            const float* __restrict__ W3,
                                                            const float* __restrict__ b3,
                                                            float* __restrict__ out) {
    __shared__ float sW2[64 * 64];     // 16 KB
    __shared__ float sW3[64 * 128];    // 32 KB
    __shared__ int   nslot[4][16];     // per-wave neighbor slots (wave-private)

    const int tid  = threadIdx.x;
    const int lane = tid & 63;
    const int wave = tid >> 6;

    // stage W2/W3 (float4 vectorized), once per 4 queries
    {
        const float4* s2 = (const float4*)W2;
        float4*       d2 = (float4*)sW2;
        for (int i = tid; i < 64 * 64 / 4; i += 256) d2[i] = s2[i];
        const float4* s3 = (const float4*)W3;
        float4*       d3 = (float4*)sW3;
        for (int i = tid; i < 64 * 128 / 4; i += 256) d3[i] = s3[i];
    }
    // per-lane weight registers (lane = channel)
    float w1c[6];
#pragma unroll
    for (int c = 0; c < 6; c++) w1c[c] = W1[c * 64 + lane];
    const float bb1  = b1[lane];
    const float bb2  = b2[lane];
    const float bb3a = b3[lane];
    const float bb3b = b3[64 + lane];
    __syncthreads();

    const int q = blockIdx.x * 4 + wave;
    const int b = q >> 10;                    // q / MM
    const float qx = pos_s[q * 3 + 0];
    const float qy = pos_s[q * 3 + 1];
    const float qz = pos_s[q * 3 + 2];

    // ---- radius scan: first-16 by index within RSQ (identical semantics) ----
    if (lane < 16) nslot[wave][lane] = 0;     // wave-private init (no barrier)
    const float* pb = pos + (size_t)b * NN * 3;
    int cnt = 0;
    for (int c = 0; c < NN / 64; c++) {
        int p = c * 64 + lane;
        float px = pb[p * 3 + 0], py = pb[p * 3 + 1], pz = pb[p * 3 + 2];
        float d2 = dist2_exact(qx, qy, qz, px, py, pz);
        bool val = (d2 <= RSQ);
        unsigned long long msk = __ballot(val);
        if (val) {
            int rank = __popcll(msk & ((1ull << lane) - 1ull));
            int slot = cnt + rank;
            if (slot < KK) nslot[wave][slot] = p;
        }
        cnt += __popcll(msk);
        if (cnt >= KK) break;
    }
    const int cnt16 = min(cnt, KK);

    // neighbor indices (wave-uniform LDS broadcast reads)
    const int4 n0 = *(const int4*)&nslot[wave][0];
    const int4 n1 = *(const int4*)&nslot[wave][4];
    const int4 n2 = *(const int4*)&nslot[wave][8];
    const int4 n3 = *(const int4*)&nslot[wave][12];
    const int nidx[16] = { n0.x, n0.y, n0.z, n0.w, n1.x, n1.y, n1.z, n1.w,
                           n2.x, n2.y, n2.z, n2.w, n3.x, n3.y, n3.z, n3.w };

    // ---- layer 1: h[e] in registers (lane = channel), validity mask ----
    float h[17];
    unsigned vmask = 1u << 16;                // self edge always valid
#pragma unroll
    for (int e = 0; e < 16; e++) {
        const int p = (e < cnt16) ? nidx[e] : 0;
        const int g = b * NN + p;
        if ((e < cnt16) && (g != q)) vmask |= (1u << e);
        const float f0 = x[(size_t)g * 3 + 0];
        const float f1 = x[(size_t)g * 3 + 1];
        const float f2 = x[(size_t)g * 3 + 2];
        const float f3 = pos[(size_t)g * 3 + 0] - qx;
        const float f4 = pos[(size_t)g * 3 + 1] - qy;
        const float f5 = pos[(size_t)g * 3 + 2] - qz;
        float t = bb1 + f0 * w1c[0] + f1 * w1c[1] + f2 * w1c[2]
                      + f3 * w1c[3] + f4 * w1c[4] + f5 * w1c[5];
        h[e] = fmaxf(t, 0.0f);
    }
    {   // added self-loop: source row q of x/pos (PyG numeric quirk)
        const int g = q;
        const float f0 = x[(size_t)g * 3 + 0];
        const float f1 = x[(size_t)g * 3 + 1];
        const float f2 = x[(size_t)g * 3 + 2];
        const float f3 = pos[(size_t)g * 3 + 0] - qx;
        const float f4 = pos[(size_t)g * 3 + 1] - qy;
        const float f5 = pos[(size_t)g * 3 + 2] - qz;
        float t = bb1 + f0 * w1c[0] + f1 * w1c[1] + f2 * w1c[2]
                      + f3 * w1c[3] + f4 * w1c[4] + f5 * w1c[5];
        h[16] = fmaxf(t, 0.0f);
    }

    // ---- layer 2: readlane broadcast (VALU) + one ds W-read per j ----
    float acc[17];
#pragma unroll
    for (int e = 0; e < 17; e++) acc[e] = bb2;
#pragma unroll 2
    for (int j = 0; j < 64; j++) {
        const float wj = sW2[j * 64 + lane];
#pragma unroll
        for (int e = 0; e < 17; e++) {
            const float hj = readlane_f(h[e], j);
            acc[e] = __builtin_fmaf(hj, wj, acc[e]);
        }
    }
#pragma unroll
    for (int e = 0; e < 17; e++) h[e] = fmaxf(acc[e], 0.0f);

    // ---- layer 3: 2 channels/lane, readlane broadcast ----
    float a0[17], a1[17];
#pragma unroll
    for (int e = 0; e < 17; e++) { a0[e] = bb3a; a1[e] = bb3b; }
#pragma unroll 2
    for (int j = 0; j < 64; j++) {
        const float wa = sW3[j * 128 + lane];
        const float wb = sW3[j * 128 + 64 + lane];
#pragma unroll
        for (int e = 0; e < 17; e++) {
            const float hj = readlane_f(h[e], j);
            a0[e] = __builtin_fmaf(hj, wa, a0[e]);
            a1[e] = __builtin_fmaf(hj, wb, a1[e]);
        }
    }

    // ---- masked max over edges (order-insensitive) ----
    float m0 = -INFINITY, m1 = -INFINITY;
#pragma unroll
    for (int e = 0; e < 17; e++) {
        const bool v = (vmask >> e) & 1u;
        m0 = v ? fmaxf(m0, a0[e]) : m0;
        m1 = v ? fmaxf(m1, a1[e]) : m1;
    }
    out[(size_t)q * COUT + lane]      = m0;
    out[(size_t)q * COUT + 64 + lane] = m1;
}

// ---------------------------------------------------------------------------
extern "C" void kernel_launch(void* const* d_in, const int* in_sizes, int n_in,
                              void* d_out, int out_size, void* d_ws, size_t ws_size,
                              hipStream_t stream) {
    const float* x   = (const float*)d_in[0];
    const float* pos = (const float*)d_in[1];
    // d_in[2] = batch (unused: layout is implicit)
    const float* W1 = (const float*)d_in[3];
    const float* b1 = (const float*)d_in[4];
    const float* W2 = (const float*)d_in[5];
    const float* b2 = (const float*)d_in[6];
    const float* W3 = (const float*)d_in[7];
    const float* b3 = (const float*)d_in[8];

    float* outF    = (float*)d_out;
    float* out     = outF;                                  // [B*M, 128]
    float* pos_s   = outF + (size_t)BB * MM * COUT;         // [B*M, 3]
    float* batch_s = pos_s + (size_t)BB * MM * 3;           // [B*M]

    fps_kernel<<<BB, 256, 0, stream>>>(pos, pos_s, batch_s);
    radius_mlp_kernel<<<BB * MM / 4, 256, 0, stream>>>(x, pos, pos_s,
                                                       W1, b1, W2, b2, W3, b3, out);
}

// Round 16
// 826.722 us; speedup vs baseline: 1.2456x; 1.1527x over previous
//
#include <hip/hip_runtime.h>
#include <hip/hip_bf16.h>
#include <math.h>

// Problem constants
constexpr int BB   = 8;
constexpr int NN   = 4096;
constexpr int MM   = 1024;
constexpr int KK   = 16;
constexpr int COUT = 128;
constexpr int NWRK = 992;    // worker waves: (256-8) blocks * 4 waves
#define RSQ 0.09f

__device__ __forceinline__ float dist2_exact(float ax, float ay, float az,
                                             float bx, float by, float bz) {
    // (a-b)^2 summed, no fma contraction: match numpy mul-then-add semantics
    float dx = __fsub_rn(ax, bx);
    float dy = __fsub_rn(ay, by);
    float dz = __fsub_rn(az, bz);
    return __fadd_rn(__fadd_rn(__fmul_rn(dx, dx), __fmul_rn(dy, dy)), __fmul_rn(dz, dz));
}

template<int CTRL>
__device__ __forceinline__ unsigned dpp_mov_u(unsigned v) {
    return (unsigned)__builtin_amdgcn_update_dpp((int)v, (int)v, CTRL, 0xF, 0xF, false);
}
__device__ __forceinline__ float readlane_f(float v, int j) {
    return __int_as_float(__builtin_amdgcn_readlane(__float_as_int(v), j));
}
__device__ __forceinline__ unsigned umax2(unsigned a, unsigned b) { return a > b ? a : b; }
__device__ __forceinline__ unsigned umin2(unsigned a, unsigned b) { return a < b ? a : b; }

// ---------------------------------------------------------------------------
// FUSED producer-consumer kernel, 256 blocks (= CU count), 1 block/CU by LDS
// (119 KB/block) -> full co-residency, no scheduling deadlock.
//
// Blocks 0..7  (producers): r13 FPS verbatim (702us — r14/r15 variants
//   reverted) + ONE relaxed agent-scope global store of the selection index
//   per iteration (gsel[q] = fi+1). Fire-and-forget: nothing after it waits
//   on vmcnt, so the r1-r4 store-drain poison does not reappear.
// Blocks 8..255 (consumers): 992 waves; wave W owns queries q = W + 992k
//   (unique coverage of [0,8192)). Each is polled (agent-scope relaxed load)
//   and processed in AVAILABILITY order with the r12 radius+mlp body; the
//   query position is recomputed from the immutable pos[] input via the
//   published index (bit-identical to pos_s, ordering-free -> relaxed safe
//   across XCDs). Spin bound fails loudly (absmax) instead of hanging.
// Query q=(b,m) becomes available at fps iteration m (~0.69us*m), so ~all
// consumer work hides under the 700us producer; tail = last selections,
// spread over ~64 distinct waves.
// ---------------------------------------------------------------------------
__global__ __launch_bounds__(256, 1) void fused_kernel(const float* __restrict__ x,
                                                       const float* __restrict__ pos,
                                                       const float* __restrict__ W1,
                                                       const float* __restrict__ b1,
                                                       const float* __restrict__ W2,
                                                       const float* __restrict__ b2,
                                                       const float* __restrict__ W3,
                                                       const float* __restrict__ b3,
                                                       unsigned* __restrict__ gsel,
                                                       float* __restrict__ out,
                                                       float* __restrict__ pos_s,
                                                       float* __restrict__ batch_s) {
    // producer LDS
    __shared__ float4 spos[NN];                       // 64 KB
    __shared__ int    shist[MM];                      // 4 KB
    __shared__ unsigned long long slotK[2][4];
    // consumer LDS
    __shared__ float sW2[64 * 64];                    // 16 KB
    __shared__ float sW3[64 * 128];                   // 32 KB
    __shared__ int   nslot[4][16];

    const int tid  = threadIdx.x;
    const int lane = tid & 63;
    const int wave = tid >> 6;

    if (blockIdx.x < BB) {
        // =================== PRODUCER: FPS (r13 verbatim) ===================
        const int b = blockIdx.x;
        const float* pb = pos + (size_t)b * NN * 3;

        for (int i = tid; i < NN; i += 256)
            spos[i] = make_float4(pb[i * 3 + 0], pb[i * 3 + 1], pb[i * 3 + 2], 0.0f);
        for (int i = tid; i < MM; i += 256)
            batch_s[(size_t)b * MM + i] = (float)b;
        if (tid == 0) {
            shist[0] = 0;
            __hip_atomic_store(&gsel[(size_t)b * MM], 1u, __ATOMIC_RELAXED,
                               __HIP_MEMORY_SCOPE_AGENT);   // m=0 -> point 0
        }
        if (tid < 8) slotK[tid >> 2][tid & 3] = 0ull;
        __syncthreads();

        float px[16], py[16], pz[16], d[16];
        const float4 p0 = spos[0];
#pragma unroll
        for (int k = 0; k < 16; k++) {
            float4 pt = spos[tid + k * 256];
            px[k] = pt.x; py[k] = pt.y; pz[k] = pt.z;
            d[k] = dist2_exact(pt.x, pt.y, pt.z, p0.x, p0.y, p0.z);
        }
        float bv;
        {
            float t1[8], t2[4];
#pragma unroll
            for (int k = 0; k < 8; k++) t1[k] = fmaxf(d[2 * k], d[2 * k + 1]);
#pragma unroll
            for (int k = 0; k < 4; k++) t2[k] = fmaxf(t1[2 * k], t1[2 * k + 1]);
            bv = fmaxf(fmaxf(t2[0], t2[1]), fmaxf(t2[2], t2[3]));
        }

        for (int m = 1; m < MM; m++) {
            const int par = m & 1;
            const unsigned tagm = (unsigned)m;

            const unsigned bvb = __float_as_uint(bv);

            unsigned rv = bvb;
            rv = umax2(rv, dpp_mov_u<0x111>(rv));
            rv = umax2(rv, dpp_mov_u<0x112>(rv));
            rv = umax2(rv, dpp_mov_u<0x114>(rv));
            rv = umax2(rv, dpp_mov_u<0x118>(rv));
            const unsigned r0 = (unsigned)__builtin_amdgcn_readlane((int)rv, 15);
            const unsigned r1 = (unsigned)__builtin_amdgcn_readlane((int)rv, 31);
            const unsigned r2 = (unsigned)__builtin_amdgcn_readlane((int)rv, 47);
            const unsigned r3 = (unsigned)__builtin_amdgcn_readlane((int)rv, 63);
            const unsigned vstar = umax2(umax2(r0, r1), umax2(r2, r3));

            unsigned kmask = 0u;
#pragma unroll
            for (int k = 0; k < 16; k++)
                kmask |= (d[k] == bv) ? (1u << k) : 0u;
            const unsigned bi = (unsigned)(tid + (__builtin_ctz(kmask) << 8));

            unsigned cand = (bvb == vstar) ? bi : 0xFFFFFFFFu;
            cand = umin2(cand, dpp_mov_u<0x111>(cand));
            cand = umin2(cand, dpp_mov_u<0x112>(cand));
            cand = umin2(cand, dpp_mov_u<0x114>(cand));
            cand = umin2(cand, dpp_mov_u<0x118>(cand));
            const unsigned c0 = (unsigned)__builtin_amdgcn_readlane((int)cand, 15);
            const unsigned c1 = (unsigned)__builtin_amdgcn_readlane((int)cand, 31);
            const unsigned c2 = (unsigned)__builtin_amdgcn_readlane((int)cand, 47);
            const unsigned c3 = (unsigned)__builtin_amdgcn_readlane((int)cand, 63);
            const unsigned wcand = umin2(umin2(c0, c1), umin2(c2, c3));

            if (lane == 0) {
                const unsigned long long key =
                    ((unsigned long long)vstar << 32)
                    | (unsigned long long)(((4095u - wcand) << 10) | tagm);
                __hip_atomic_store(&slotK[par][wave], key, __ATOMIC_RELAXED,
                                   __HIP_MEMORY_SCOPE_WORKGROUP);
            }

            unsigned long long k0, k1, k2, k3;
            for (;;) {
                k0 = __hip_atomic_load(&slotK[par][0], __ATOMIC_RELAXED, __HIP_MEMORY_SCOPE_WORKGROUP);
                k1 = __hip_atomic_load(&slotK[par][1], __ATOMIC_RELAXED, __HIP_MEMORY_SCOPE_WORKGROUP);
                k2 = __hip_atomic_load(&slotK[par][2], __ATOMIC_RELAXED, __HIP_MEMORY_SCOPE_WORKGROUP);
                k3 = __hip_atomic_load(&slotK[par][3], __ATOMIC_RELAXED, __HIP_MEMORY_SCOPE_WORKGROUP);
                bool ok = (((unsigned)k0 & 1023u) == tagm) &
                          (((unsigned)k1 & 1023u) == tagm) &
                          (((unsigned)k2 & 1023u) == tagm) &
                          (((unsigned)k3 & 1023u) == tagm);
                if (ok) break;
            }

            unsigned long long kA = (k0 > k1) ? k0 : k1;
            unsigned long long kB = (k2 > k3) ? k2 : k3;
            unsigned long long kk = (kA > kB) ? kA : kB;
            const int fi = 4095 - (int)(((unsigned)kk >> 10) & 4095u);

            if (tid == 0) {
                shist[m] = fi;
                // publish selection (fire-and-forget; nothing waits on vmcnt)
                __hip_atomic_store(&gsel[(size_t)b * MM + m], (unsigned)(fi + 1),
                                   __ATOMIC_RELAXED, __HIP_MEMORY_SCOPE_AGENT);
            }

            const float4 sp = spos[fi];
            if (m < MM - 1) {
#pragma unroll
                for (int k = 0; k < 16; k++) {
                    float nd = dist2_exact(px[k], py[k], pz[k], sp.x, sp.y, sp.z);
                    d[k] = fminf(d[k], nd);
                }
                float t1[8], t2[4];
#pragma unroll
                for (int k = 0; k < 8; k++) t1[k] = fmaxf(d[2 * k], d[2 * k + 1]);
#pragma unroll
                for (int k = 0; k < 4; k++) t2[k] = fmaxf(t1[2 * k], t1[2 * k + 1]);
                bv = fmaxf(fmaxf(t2[0], t2[1]), fmaxf(t2[2], t2[3]));
            }
        }

        __syncthreads();
        for (int i = tid; i < MM; i += 256) {
            float4 sp = spos[shist[i]];
            size_t o = (size_t)b * MM + i;
            pos_s[o * 3 + 0] = sp.x;
            pos_s[o * 3 + 1] = sp.y;
            pos_s[o * 3 + 2] = sp.z;
        }
        return;
    }

    // ===================== CONSUMER: radius + MLP =====================
    {
        const float4* s2 = (const float4*)W2;
        float4*       d2 = (float4*)sW2;
        for (int i = tid; i < 64 * 64 / 4; i += 256) d2[i] = s2[i];
        const float4* s3 = (const float4*)W3;
        float4*       d3 = (float4*)sW3;
        for (int i = tid; i < 64 * 128 / 4; i += 256) d3[i] = s3[i];
    }
    float w1c[6];
#pragma unroll
    for (int c = 0; c < 6; c++) w1c[c] = W1[c * 64 + lane];
    const float bb1  = b1[lane];
    const float bb2  = b2[lane];
    const float bb3a = b3[lane];
    const float bb3b = b3[64 + lane];
    __syncthreads();

    const int W = (blockIdx.x - BB) * 4 + wave;    // 0..991

    // queries q = W + 992k; todo bitmask over k
    unsigned todo = 0u;
#pragma unroll
    for (int k = 0; k < 9; k++)
        if (W + NWRK * k < BB * MM) todo |= (1u << k);

    int guard = 0;
    while (todo) {
        if (++guard > 200000) break;               // fail loudly, never hang
#pragma unroll
        for (int k = 0; k < 9; k++) {
            if (!((todo >> k) & 1u)) continue;
            const int q = W + NWRK * k;
            const unsigned v = __hip_atomic_load(&gsel[q], __ATOMIC_RELAXED,
                                                 __HIP_MEMORY_SCOPE_AGENT);
            if (v == 0u || v > (unsigned)NN) continue;   // not yet published
            todo &= ~(1u << k);

            // ---------- process query q (r12 body; qpos from pos[]) ----------
            const int b  = q >> 10;
            const int fi = (int)v - 1;
            const float qx = pos[((size_t)b * NN + fi) * 3 + 0];
            const float qy = pos[((size_t)b * NN + fi) * 3 + 1];
            const float qz = pos[((size_t)b * NN + fi) * 3 + 2];

            // radius scan: first-16 by index within RSQ (identical semantics)
            if (lane < 16) nslot[wave][lane] = 0;
            const float* pb = pos + (size_t)b * NN * 3;
            int cnt = 0;
            for (int c = 0; c < NN / 64; c++) {
                int p = c * 64 + lane;
                float px = pb[p * 3 + 0], py = pb[p * 3 + 1], pz = pb[p * 3 + 2];
                float d2 = dist2_exact(qx, qy, qz, px, py, pz);
                bool val = (d2 <= RSQ);
                unsigned long long msk = __ballot(val);
                if (val) {
                    int rank = __popcll(msk & ((1ull << lane) - 1ull));
                    int slot = cnt + rank;
                    if (slot < KK) nslot[wave][slot] = p;
                }
                cnt += __popcll(msk);
                if (cnt >= KK) break;
            }
            const int cnt16 = min(cnt, KK);

            const int4 n0 = *(const int4*)&nslot[wave][0];
            const int4 n1 = *(const int4*)&nslot[wave][4];
            const int4 n2 = *(const int4*)&nslot[wave][8];
            const int4 n3 = *(const int4*)&nslot[wave][12];
            const int nidx[16] = { n0.x, n0.y, n0.z, n0.w, n1.x, n1.y, n1.z, n1.w,
                                   n2.x, n2.y, n2.z, n2.w, n3.x, n3.y, n3.z, n3.w };

            // layer 1
            float h[17];
            unsigned vmask = 1u << 16;
#pragma unroll
            for (int e = 0; e < 16; e++) {
                const int p = (e < cnt16) ? nidx[e] : 0;
                const int g = b * NN + p;
                if ((e < cnt16) && (g != q)) vmask |= (1u << e);
                const float f0 = x[(size_t)g * 3 + 0];
                const float f1 = x[(size_t)g * 3 + 1];
                const float f2 = x[(size_t)g * 3 + 2];
                const float f3 = pos[(size_t)g * 3 + 0] - qx;
                const float f4 = pos[(size_t)g * 3 + 1] - qy;
                const float f5 = pos[(size_t)g * 3 + 2] - qz;
                float t = bb1 + f0 * w1c[0] + f1 * w1c[1] + f2 * w1c[2]
                              + f3 * w1c[3] + f4 * w1c[4] + f5 * w1c[5];
                h[e] = fmaxf(t, 0.0f);
            }
            {   // added self-loop (PyG numeric quirk)
                const int g = q;
                const float f0 = x[(size_t)g * 3 + 0];
                const float f1 = x[(size_t)g * 3 + 1];
                const float f2 = x[(size_t)g * 3 + 2];
                const float f3 = pos[(size_t)g * 3 + 0] - qx;
                const float f4 = pos[(size_t)g * 3 + 1] - qy;
                const float f5 = pos[(size_t)g * 3 + 2] - qz;
                float t = bb1 + f0 * w1c[0] + f1 * w1c[1] + f2 * w1c[2]
                              + f3 * w1c[3] + f4 * w1c[4] + f5 * w1c[5];
                h[16] = fmaxf(t, 0.0f);
            }

            // layer 2
            float acc[17];
#pragma unroll
            for (int e = 0; e < 17; e++) acc[e] = bb2;
#pragma unroll 2
            for (int j = 0; j < 64; j++) {
                const float wj = sW2[j * 64 + lane];
#pragma unroll
                for (int e = 0; e < 17; e++) {
                    const float hj = readlane_f(h[e], j);
                    acc[e] = __builtin_fmaf(hj, wj, acc[e]);
                }
            }
#pragma unroll
            for (int e = 0; e < 17; e++) h[e] = fmaxf(acc[e], 0.0f);

            // layer 3
            float a0[17], a1[17];
#pragma unroll
            for (int e = 0; e < 17; e++) { a0[e] = bb3a; a1[e] = bb3b; }
#pragma unroll 2
            for (int j = 0; j < 64; j++) {
                const float wa = sW3[j * 128 + lane];
                const float wb = sW3[j * 128 + 64 + lane];
#pragma unroll
                for (int e = 0; e < 17; e++) {
                    const float hj = readlane_f(h[e], j);
                    a0[e] = __builtin_fmaf(hj, wa, a0[e]);
                    a1[e] = __builtin_fmaf(hj, wb, a1[e]);
                }
            }

            // masked max
            float m0 = -INFINITY, m1 = -INFINITY;
#pragma unroll
            for (int e = 0; e < 17; e++) {
                const bool vv = (vmask >> e) & 1u;
                m0 = vv ? fmaxf(m0, a0[e]) : m0;
                m1 = vv ? fmaxf(m1, a1[e]) : m1;
            }
            out[(size_t)q * COUT + lane]      = m0;
            out[(size_t)q * COUT + 64 + lane] = m1;
        }
    }
}

// ---------------------------------------------------------------------------
extern "C" void kernel_launch(void* const* d_in, const int* in_sizes, int n_in,
                              void* d_out, int out_size, void* d_ws, size_t ws_size,
                              hipStream_t stream) {
    const float* x   = (const float*)d_in[0];
    const float* pos = (const float*)d_in[1];
    // d_in[2] = batch (unused: layout is implicit)
    const float* W1 = (const float*)d_in[3];
    const float* b1 = (const float*)d_in[4];
    const float* W2 = (const float*)d_in[5];
    const float* b2 = (const float*)d_in[6];
    const float* W3 = (const float*)d_in[7];
    const float* b3 = (const float*)d_in[8];

    float* outF    = (float*)d_out;
    float* out     = outF;                                  // [B*M, 128]
    float* pos_s   = outF + (size_t)BB * MM * COUT;         // [B*M, 3]
    float* batch_s = pos_s + (size_t)BB * MM * 3;           // [B*M]

    unsigned* gsel = (unsigned*)d_ws;                       // [B*M] selection index+1

    hipMemsetAsync(gsel, 0, (size_t)BB * MM * sizeof(unsigned), stream);

    fused_kernel<<<256, 256, 0, stream>>>(x, pos, W1, b1, W2, b2, W3, b3,
                                          gsel, out, pos_s, batch_s);
}

// Round 17
// 818.625 us; speedup vs baseline: 1.2579x; 1.0099x over previous
//
#include <hip/hip_runtime.h>
#include <hip/hip_bf16.h>
#include <math.h>

// Problem constants
constexpr int BB   = 8;
constexpr int NN   = 4096;
constexpr int MM   = 1024;
constexpr int KK   = 16;
constexpr int COUT = 128;
constexpr int NWRK = 992;    // worker waves: (256-8) blocks * 4 waves
#define RSQ 0.09f

__device__ __forceinline__ float dist2_exact(float ax, float ay, float az,
                                             float bx, float by, float bz) {
    // (a-b)^2 summed, no fma contraction: match numpy mul-then-add semantics
    float dx = __fsub_rn(ax, bx);
    float dy = __fsub_rn(ay, by);
    float dz = __fsub_rn(az, bz);
    return __fadd_rn(__fadd_rn(__fmul_rn(dx, dx), __fmul_rn(dy, dy)), __fmul_rn(dz, dz));
}

template<int CTRL>
__device__ __forceinline__ unsigned dpp_mov_u(unsigned v) {
    return (unsigned)__builtin_amdgcn_update_dpp((int)v, (int)v, CTRL, 0xF, 0xF, false);
}
__device__ __forceinline__ float readlane_f(float v, int j) {
    return __int_as_float(__builtin_amdgcn_readlane(__float_as_int(v), j));
}
__device__ __forceinline__ unsigned umax2(unsigned a, unsigned b) { return a > b ? a : b; }
__device__ __forceinline__ unsigned umin2(unsigned a, unsigned b) { return a < b ? a : b; }

// ---------------------------------------------------------------------------
// FUSED producer-consumer kernel (r16 structure, 827us total).
//
// r16 -> r17 (single variable): consumers SLEEP between poll rounds
// (s_sleep ~2048cyc) instead of hot-spinning. r16 evidence: 992 spinning
// waves (VALUBusy 17%, FETCH 4MB of poll traffic) cost the 8 producer CUs
// ~10% via the shared power/boost budget (producer 702us standalone -> 773us
// fused) — same signature as the r4/r7 heater experiments. Sleeping waves
// idle their SIMD slot and draw ~no power; tail latency added per query is
// <= one sleep quantum (~0.85us, negligible vs the ~25us tail).
// ---------------------------------------------------------------------------
__global__ __launch_bounds__(256, 1) void fused_kernel(const float* __restrict__ x,
                                                       const float* __restrict__ pos,
                                                       const float* __restrict__ W1,
                                                       const float* __restrict__ b1,
                                                       const float* __restrict__ W2,
                                                       const float* __restrict__ b2,
                                                       const float* __restrict__ W3,
                                                       const float* __restrict__ b3,
                                                       unsigned* __restrict__ gsel,
                                                       float* __restrict__ out,
                                                       float* __restrict__ pos_s,
                                                       float* __restrict__ batch_s) {
    // producer LDS
    __shared__ float4 spos[NN];                       // 64 KB
    __shared__ int    shist[MM];                      // 4 KB
    __shared__ unsigned long long slotK[2][4];
    // consumer LDS
    __shared__ float sW2[64 * 64];                    // 16 KB
    __shared__ float sW3[64 * 128];                   // 32 KB
    __shared__ int   nslot[4][16];

    const int tid  = threadIdx.x;
    const int lane = tid & 63;
    const int wave = tid >> 6;

    if (blockIdx.x < BB) {
        // =================== PRODUCER: FPS (r13 verbatim) ===================
        const int b = blockIdx.x;
        const float* pb = pos + (size_t)b * NN * 3;

        for (int i = tid; i < NN; i += 256)
            spos[i] = make_float4(pb[i * 3 + 0], pb[i * 3 + 1], pb[i * 3 + 2], 0.0f);
        for (int i = tid; i < MM; i += 256)
            batch_s[(size_t)b * MM + i] = (float)b;
        if (tid == 0) {
            shist[0] = 0;
            __hip_atomic_store(&gsel[(size_t)b * MM], 1u, __ATOMIC_RELAXED,
                               __HIP_MEMORY_SCOPE_AGENT);   // m=0 -> point 0
        }
        if (tid < 8) slotK[tid >> 2][tid & 3] = 0ull;
        __syncthreads();

        float px[16], py[16], pz[16], d[16];
        const float4 p0 = spos[0];
#pragma unroll
        for (int k = 0; k < 16; k++) {
            float4 pt = spos[tid + k * 256];
            px[k] = pt.x; py[k] = pt.y; pz[k] = pt.z;
            d[k] = dist2_exact(pt.x, pt.y, pt.z, p0.x, p0.y, p0.z);
        }
        float bv;
        {
            float t1[8], t2[4];
#pragma unroll
            for (int k = 0; k < 8; k++) t1[k] = fmaxf(d[2 * k], d[2 * k + 1]);
#pragma unroll
            for (int k = 0; k < 4; k++) t2[k] = fmaxf(t1[2 * k], t1[2 * k + 1]);
            bv = fmaxf(fmaxf(t2[0], t2[1]), fmaxf(t2[2], t2[3]));
        }

        for (int m = 1; m < MM; m++) {
            const int par = m & 1;
            const unsigned tagm = (unsigned)m;

            const unsigned bvb = __float_as_uint(bv);

            unsigned rv = bvb;
            rv = umax2(rv, dpp_mov_u<0x111>(rv));
            rv = umax2(rv, dpp_mov_u<0x112>(rv));
            rv = umax2(rv, dpp_mov_u<0x114>(rv));
            rv = umax2(rv, dpp_mov_u<0x118>(rv));
            const unsigned r0 = (unsigned)__builtin_amdgcn_readlane((int)rv, 15);
            const unsigned r1 = (unsigned)__builtin_amdgcn_readlane((int)rv, 31);
            const unsigned r2 = (unsigned)__builtin_amdgcn_readlane((int)rv, 47);
            const unsigned r3 = (unsigned)__builtin_amdgcn_readlane((int)rv, 63);
            const unsigned vstar = umax2(umax2(r0, r1), umax2(r2, r3));

            unsigned kmask = 0u;
#pragma unroll
            for (int k = 0; k < 16; k++)
                kmask |= (d[k] == bv) ? (1u << k) : 0u;
            const unsigned bi = (unsigned)(tid + (__builtin_ctz(kmask) << 8));

            unsigned cand = (bvb == vstar) ? bi : 0xFFFFFFFFu;
            cand = umin2(cand, dpp_mov_u<0x111>(cand));
            cand = umin2(cand, dpp_mov_u<0x112>(cand));
            cand = umin2(cand, dpp_mov_u<0x114>(cand));
            cand = umin2(cand, dpp_mov_u<0x118>(cand));
            const unsigned c0 = (unsigned)__builtin_amdgcn_readlane((int)cand, 15);
            const unsigned c1 = (unsigned)__builtin_amdgcn_readlane((int)cand, 31);
            const unsigned c2 = (unsigned)__builtin_amdgcn_readlane((int)cand, 47);
            const unsigned c3 = (unsigned)__builtin_amdgcn_readlane((int)cand, 63);
            const unsigned wcand = umin2(umin2(c0, c1), umin2(c2, c3));

            if (lane == 0) {
                const unsigned long long key =
                    ((unsigned long long)vstar << 32)
                    | (unsigned long long)(((4095u - wcand) << 10) | tagm);
                __hip_atomic_store(&slotK[par][wave], key, __ATOMIC_RELAXED,
                                   __HIP_MEMORY_SCOPE_WORKGROUP);
            }

            unsigned long long k0, k1, k2, k3;
            for (;;) {
                k0 = __hip_atomic_load(&slotK[par][0], __ATOMIC_RELAXED, __HIP_MEMORY_SCOPE_WORKGROUP);
                k1 = __hip_atomic_load(&slotK[par][1], __ATOMIC_RELAXED, __HIP_MEMORY_SCOPE_WORKGROUP);
                k2 = __hip_atomic_load(&slotK[par][2], __ATOMIC_RELAXED, __HIP_MEMORY_SCOPE_WORKGROUP);
                k3 = __hip_atomic_load(&slotK[par][3], __ATOMIC_RELAXED, __HIP_MEMORY_SCOPE_WORKGROUP);
                bool ok = (((unsigned)k0 & 1023u) == tagm) &
                          (((unsigned)k1 & 1023u) == tagm) &
                          (((unsigned)k2 & 1023u) == tagm) &
                          (((unsigned)k3 & 1023u) == tagm);
                if (ok) break;
            }

            unsigned long long kA = (k0 > k1) ? k0 : k1;
            unsigned long long kB = (k2 > k3) ? k2 : k3;
            unsigned long long kk = (kA > kB) ? kA : kB;
            const int fi = 4095 - (int)(((unsigned)kk >> 10) & 4095u);

            if (tid == 0) {
                shist[m] = fi;
                // publish selection (fire-and-forget; nothing waits on vmcnt)
                __hip_atomic_store(&gsel[(size_t)b * MM + m], (unsigned)(fi + 1),
                                   __ATOMIC_RELAXED, __HIP_MEMORY_SCOPE_AGENT);
            }

            const float4 sp = spos[fi];
            if (m < MM - 1) {
#pragma unroll
                for (int k = 0; k < 16; k++) {
                    float nd = dist2_exact(px[k], py[k], pz[k], sp.x, sp.y, sp.z);
                    d[k] = fminf(d[k], nd);
                }
                float t1[8], t2[4];
#pragma unroll
                for (int k = 0; k < 8; k++) t1[k] = fmaxf(d[2 * k], d[2 * k + 1]);
#pragma unroll
                for (int k = 0; k < 4; k++) t2[k] = fmaxf(t1[2 * k], t1[2 * k + 1]);
                bv = fmaxf(fmaxf(t2[0], t2[1]), fmaxf(t2[2], t2[3]));
            }
        }

        __syncthreads();
        for (int i = tid; i < MM; i += 256) {
            float4 sp = spos[shist[i]];
            size_t o = (size_t)b * MM + i;
            pos_s[o * 3 + 0] = sp.x;
            pos_s[o * 3 + 1] = sp.y;
            pos_s[o * 3 + 2] = sp.z;
        }
        return;
    }

    // ===================== CONSUMER: radius + MLP =====================
    {
        const float4* s2 = (const float4*)W2;
        float4*       d2 = (float4*)sW2;
        for (int i = tid; i < 64 * 64 / 4; i += 256) d2[i] = s2[i];
        const float4* s3 = (const float4*)W3;
        float4*       d3 = (float4*)sW3;
        for (int i = tid; i < 64 * 128 / 4; i += 256) d3[i] = s3[i];
    }
    float w1c[6];
#pragma unroll
    for (int c = 0; c < 6; c++) w1c[c] = W1[c * 64 + lane];
    const float bb1  = b1[lane];
    const float bb2  = b2[lane];
    const float bb3a = b3[lane];
    const float bb3b = b3[64 + lane];
    __syncthreads();

    const int W = (blockIdx.x - BB) * 4 + wave;    // 0..991

    // queries q = W + 992k; todo bitmask over k
    unsigned todo = 0u;
#pragma unroll
    for (int k = 0; k < 9; k++)
        if (W + NWRK * k < BB * MM) todo |= (1u << k);

    int guard = 0;
    while (todo) {
        if (++guard > 20000) break;                // fail loudly, never hang
        const unsigned todo_in = todo;
#pragma unroll
        for (int k = 0; k < 9; k++) {
            if (!((todo >> k) & 1u)) continue;
            const int q = W + NWRK * k;
            const unsigned v = __hip_atomic_load(&gsel[q], __ATOMIC_RELAXED,
                                                 __HIP_MEMORY_SCOPE_AGENT);
            if (v == 0u || v > (unsigned)NN) continue;   // not yet published
            todo &= ~(1u << k);

            // ---------- process query q (r12 body; qpos from pos[]) ----------
            const int b  = q >> 10;
            const int fi = (int)v - 1;
            const float qx = pos[((size_t)b * NN + fi) * 3 + 0];
            const float qy = pos[((size_t)b * NN + fi) * 3 + 1];
            const float qz = pos[((size_t)b * NN + fi) * 3 + 2];

            // radius scan: first-16 by index within RSQ (identical semantics)
            if (lane < 16) nslot[wave][lane] = 0;
            const float* pb = pos + (size_t)b * NN * 3;
            int cnt = 0;
            for (int c = 0; c < NN / 64; c++) {
                int p = c * 64 + lane;
                float px = pb[p * 3 + 0], py = pb[p * 3 + 1], pz = pb[p * 3 + 2];
                float d2 = dist2_exact(qx, qy, qz, px, py, pz);
                bool val = (d2 <= RSQ);
                unsigned long long msk = __ballot(val);
                if (val) {
                    int rank = __popcll(msk & ((1ull << lane) - 1ull));
                    int slot = cnt + rank;
                    if (slot < KK) nslot[wave][slot] = p;
                }
                cnt += __popcll(msk);
                if (cnt >= KK) break;
            }
            const int cnt16 = min(cnt, KK);

            const int4 n0 = *(const int4*)&nslot[wave][0];
            const int4 n1 = *(const int4*)&nslot[wave][4];
            const int4 n2 = *(const int4*)&nslot[wave][8];
            const int4 n3 = *(const int4*)&nslot[wave][12];
            const int nidx[16] = { n0.x, n0.y, n0.z, n0.w, n1.x, n1.y, n1.z, n1.w,
                                   n2.x, n2.y, n2.z, n2.w, n3.x, n3.y, n3.z, n3.w };

            // layer 1
            float h[17];
            unsigned vmask = 1u << 16;
#pragma unroll
            for (int e = 0; e < 16; e++) {
                const int p = (e < cnt16) ? nidx[e] : 0;
                const int g = b * NN + p;
                if ((e < cnt16) && (g != q)) vmask |= (1u << e);
                const float f0 = x[(size_t)g * 3 + 0];
                const float f1 = x[(size_t)g * 3 + 1];
                const float f2 = x[(size_t)g * 3 + 2];
                const float f3 = pos[(size_t)g * 3 + 0] - qx;
                const float f4 = pos[(size_t)g * 3 + 1] - qy;
                const float f5 = pos[(size_t)g * 3 + 2] - qz;
                float t = bb1 + f0 * w1c[0] + f1 * w1c[1] + f2 * w1c[2]
                              + f3 * w1c[3] + f4 * w1c[4] + f5 * w1c[5];
                h[e] = fmaxf(t, 0.0f);
            }
            {   // added self-loop (PyG numeric quirk)
                const int g = q;
                const float f0 = x[(size_t)g * 3 + 0];
                const float f1 = x[(size_t)g * 3 + 1];
                const float f2 = x[(size_t)g * 3 + 2];
                const float f3 = pos[(size_t)g * 3 + 0] - qx;
                const float f4 = pos[(size_t)g * 3 + 1] - qy;
                const float f5 = pos[(size_t)g * 3 + 2] - qz;
                float t = bb1 + f0 * w1c[0] + f1 * w1c[1] + f2 * w1c[2]
                              + f3 * w1c[3] + f4 * w1c[4] + f5 * w1c[5];
                h[16] = fmaxf(t, 0.0f);
            }

            // layer 2
            float acc[17];
#pragma unroll
            for (int e = 0; e < 17; e++) acc[e] = bb2;
#pragma unroll 2
            for (int j = 0; j < 64; j++) {
                const float wj = sW2[j * 64 + lane];
#pragma unroll
                for (int e = 0; e < 17; e++) {
                    const float hj = readlane_f(h[e], j);
                    acc[e] = __builtin_fmaf(hj, wj, acc[e]);
                }
            }
#pragma unroll
            for (int e = 0; e < 17; e++) h[e] = fmaxf(acc[e], 0.0f);

            // layer 3
            float a0[17], a1[17];
#pragma unroll
            for (int e = 0; e < 17; e++) { a0[e] = bb3a; a1[e] = bb3b; }
#pragma unroll 2
            for (int j = 0; j < 64; j++) {
                const float wa = sW3[j * 128 + lane];
                const float wb = sW3[j * 128 + 64 + lane];
#pragma unroll
                for (int e = 0; e < 17; e++) {
                    const float hj = readlane_f(h[e], j);
                    a0[e] = __builtin_fmaf(hj, wa, a0[e]);
                    a1[e] = __builtin_fmaf(hj, wb, a1[e]);
                }
            }

            // masked max
            float m0 = -INFINITY, m1 = -INFINITY;
#pragma unroll
            for (int e = 0; e < 17; e++) {
                const bool vv = (vmask >> e) & 1u;
                m0 = vv ? fmaxf(m0, a0[e]) : m0;
                m1 = vv ? fmaxf(m1, a1[e]) : m1;
            }
            out[(size_t)q * COUT + lane]      = m0;
            out[(size_t)q * COUT + 64 + lane] = m1;
        }
        // nothing became ready this round -> idle the wave (no power draw,
        // no L2 poll traffic) instead of hot-spinning
        if (todo == todo_in && todo)
            __builtin_amdgcn_s_sleep(32);          // ~2048 cyc =~ 0.85us
    }
}

// ---------------------------------------------------------------------------
extern "C" void kernel_launch(void* const* d_in, const int* in_sizes, int n_in,
                              void* d_out, int out_size, void* d_ws, size_t ws_size,
                              hipStream_t stream) {
    const float* x   = (const float*)d_in[0];
    const float* pos = (const float*)d_in[1];
    // d_in[2] = batch (unused: layout is implicit)
    const float* W1 = (const float*)d_in[3];
    const float* b1 = (const float*)d_in[4];
    const float* W2 = (const float*)d_in[5];
    const float* b2 = (const float*)d_in[6];
    const float* W3 = (const float*)d_in[7];
    const float* b3 = (const float*)d_in[8];

    float* outF    = (float*)d_out;
    float* out     = outF;                                  // [B*M, 128]
    float* pos_s   = outF + (size_t)BB * MM * COUT;         // [B*M, 3]
    float* batch_s = pos_s + (size_t)BB * MM * 3;           // [B*M]

    unsigned* gsel = (unsigned*)d_ws;                       // [B*M] selection index+1

    hipMemsetAsync(gsel, 0, (size_t)BB * MM * sizeof(unsigned), stream);

    fused_kernel<<<256, 256, 0, stream>>>(x, pos, W1, b1, W2, b2, W3, b3,
                                          gsel, out, pos_s, batch_s);
}

// Round 18
// 809.241 us; speedup vs baseline: 1.2725x; 1.0116x over previous
//
#include <hip/hip_runtime.h>
#include <hip/hip_bf16.h>
#include <math.h>

// Problem constants
constexpr int BB   = 8;
constexpr int NN   = 4096;
constexpr int MM   = 1024;
constexpr int KK   = 16;
constexpr int COUT = 128;
constexpr int NWRK = 992;    // worker waves: (256-8) blocks * 4 waves
#define RSQ 0.09f

__device__ __forceinline__ float dist2_exact(float ax, float ay, float az,
                                             float bx, float by, float bz) {
    // (a-b)^2 summed, no fma contraction: match numpy mul-then-add semantics
    float dx = __fsub_rn(ax, bx);
    float dy = __fsub_rn(ay, by);
    float dz = __fsub_rn(az, bz);
    return __fadd_rn(__fadd_rn(__fmul_rn(dx, dx), __fmul_rn(dy, dy)), __fmul_rn(dz, dz));
}

template<int CTRL>
__device__ __forceinline__ unsigned dpp_mov_u(unsigned v) {
    return (unsigned)__builtin_amdgcn_update_dpp((int)v, (int)v, CTRL, 0xF, 0xF, false);
}
__device__ __forceinline__ float readlane_f(float v, int j) {
    return __int_as_float(__builtin_amdgcn_readlane(__float_as_int(v), j));
}
__device__ __forceinline__ unsigned umax2(unsigned a, unsigned b) { return a > b ? a : b; }
__device__ __forceinline__ unsigned umin2(unsigned a, unsigned b) { return a < b ? a : b; }

// ---------------------------------------------------------------------------
// FUSED producer-consumer kernel (r16 structure).
//
// r17 -> r18: consumers wait for their queries IN AVAILABILITY ORDER.
// Wave W's queries q = W + 992k have m = (W - 32j) mod 1024 — monotone
// availability, spaced ~22us. So: sort the <=9 queries by m once, then poll
// exactly ONE gsel address at a time with the maximum sleep quantum
// (s_sleep(127) ~ 8128cyc ~ 3.4us). Poll loads drop ~9x, consumer duty
// cycle ~85% -> ~10%: tests whether the producer's +60us slowdown
// (766 fused vs 702 standalone) is consumer power draw. Producer unchanged.
// ---------------------------------------------------------------------------
__global__ __launch_bounds__(256, 1) void fused_kernel(const float* __restrict__ x,
                                                       const float* __restrict__ pos,
                                                       const float* __restrict__ W1,
                                                       const float* __restrict__ b1,
                                                       const float* __restrict__ W2,
                                                       const float* __restrict__ b2,
                                                       const float* __restrict__ W3,
                                                       const float* __restrict__ b3,
                                                       unsigned* __restrict__ gsel,
                                                       float* __restrict__ out,
                                                       float* __restrict__ pos_s,
                                                       float* __restrict__ batch_s) {
    // producer LDS
    __shared__ float4 spos[NN];                       // 64 KB
    __shared__ int    shist[MM];                      // 4 KB
    __shared__ unsigned long long slotK[2][4];
    // consumer LDS
    __shared__ float sW2[64 * 64];                    // 16 KB
    __shared__ float sW3[64 * 128];                   // 32 KB
    __shared__ int   nslot[4][16];

    const int tid  = threadIdx.x;
    const int lane = tid & 63;
    const int wave = tid >> 6;

    if (blockIdx.x < BB) {
        // =================== PRODUCER: FPS (r13 verbatim) ===================
        const int b = blockIdx.x;
        const float* pb = pos + (size_t)b * NN * 3;

        for (int i = tid; i < NN; i += 256)
            spos[i] = make_float4(pb[i * 3 + 0], pb[i * 3 + 1], pb[i * 3 + 2], 0.0f);
        for (int i = tid; i < MM; i += 256)
            batch_s[(size_t)b * MM + i] = (float)b;
        if (tid == 0) {
            shist[0] = 0;
            __hip_atomic_store(&gsel[(size_t)b * MM], 1u, __ATOMIC_RELAXED,
                               __HIP_MEMORY_SCOPE_AGENT);   // m=0 -> point 0
        }
        if (tid < 8) slotK[tid >> 2][tid & 3] = 0ull;
        __syncthreads();

        float px[16], py[16], pz[16], d[16];
        const float4 p0 = spos[0];
#pragma unroll
        for (int k = 0; k < 16; k++) {
            float4 pt = spos[tid + k * 256];
            px[k] = pt.x; py[k] = pt.y; pz[k] = pt.z;
            d[k] = dist2_exact(pt.x, pt.y, pt.z, p0.x, p0.y, p0.z);
        }
        float bv;
        {
            float t1[8], t2[4];
#pragma unroll
            for (int k = 0; k < 8; k++) t1[k] = fmaxf(d[2 * k], d[2 * k + 1]);
#pragma unroll
            for (int k = 0; k < 4; k++) t2[k] = fmaxf(t1[2 * k], t1[2 * k + 1]);
            bv = fmaxf(fmaxf(t2[0], t2[1]), fmaxf(t2[2], t2[3]));
        }

        for (int m = 1; m < MM; m++) {
            const int par = m & 1;
            const unsigned tagm = (unsigned)m;

            const unsigned bvb = __float_as_uint(bv);

            unsigned rv = bvb;
            rv = umax2(rv, dpp_mov_u<0x111>(rv));
            rv = umax2(rv, dpp_mov_u<0x112>(rv));
            rv = umax2(rv, dpp_mov_u<0x114>(rv));
            rv = umax2(rv, dpp_mov_u<0x118>(rv));
            const unsigned r0 = (unsigned)__builtin_amdgcn_readlane((int)rv, 15);
            const unsigned r1 = (unsigned)__builtin_amdgcn_readlane((int)rv, 31);
            const unsigned r2 = (unsigned)__builtin_amdgcn_readlane((int)rv, 47);
            const unsigned r3 = (unsigned)__builtin_amdgcn_readlane((int)rv, 63);
            const unsigned vstar = umax2(umax2(r0, r1), umax2(r2, r3));

            unsigned kmask = 0u;
#pragma unroll
            for (int k = 0; k < 16; k++)
                kmask |= (d[k] == bv) ? (1u << k) : 0u;
            const unsigned bi = (unsigned)(tid + (__builtin_ctz(kmask) << 8));

            unsigned cand = (bvb == vstar) ? bi : 0xFFFFFFFFu;
            cand = umin2(cand, dpp_mov_u<0x111>(cand));
            cand = umin2(cand, dpp_mov_u<0x112>(cand));
            cand = umin2(cand, dpp_mov_u<0x114>(cand));
            cand = umin2(cand, dpp_mov_u<0x118>(cand));
            const unsigned c0 = (unsigned)__builtin_amdgcn_readlane((int)cand, 15);
            const unsigned c1 = (unsigned)__builtin_amdgcn_readlane((int)cand, 31);
            const unsigned c2 = (unsigned)__builtin_amdgcn_readlane((int)cand, 47);
            const unsigned c3 = (unsigned)__builtin_amdgcn_readlane((int)cand, 63);
            const unsigned wcand = umin2(umin2(c0, c1), umin2(c2, c3));

            if (lane == 0) {
                const unsigned long long key =
                    ((unsigned long long)vstar << 32)
                    | (unsigned long long)(((4095u - wcand) << 10) | tagm);
                __hip_atomic_store(&slotK[par][wave], key, __ATOMIC_RELAXED,
                                   __HIP_MEMORY_SCOPE_WORKGROUP);
            }

            unsigned long long k0, k1, k2, k3;
            for (;;) {
                k0 = __hip_atomic_load(&slotK[par][0], __ATOMIC_RELAXED, __HIP_MEMORY_SCOPE_WORKGROUP);
                k1 = __hip_atomic_load(&slotK[par][1], __ATOMIC_RELAXED, __HIP_MEMORY_SCOPE_WORKGROUP);
                k2 = __hip_atomic_load(&slotK[par][2], __ATOMIC_RELAXED, __HIP_MEMORY_SCOPE_WORKGROUP);
                k3 = __hip_atomic_load(&slotK[par][3], __ATOMIC_RELAXED, __HIP_MEMORY_SCOPE_WORKGROUP);
                bool ok = (((unsigned)k0 & 1023u) == tagm) &
                          (((unsigned)k1 & 1023u) == tagm) &
                          (((unsigned)k2 & 1023u) == tagm) &
                          (((unsigned)k3 & 1023u) == tagm);
                if (ok) break;
            }

            unsigned long long kA = (k0 > k1) ? k0 : k1;
            unsigned long long kB = (k2 > k3) ? k2 : k3;
            unsigned long long kk = (kA > kB) ? kA : kB;
            const int fi = 4095 - (int)(((unsigned)kk >> 10) & 4095u);

            if (tid == 0) {
                shist[m] = fi;
                // publish selection (fire-and-forget; nothing waits on vmcnt)
                __hip_atomic_store(&gsel[(size_t)b * MM + m], (unsigned)(fi + 1),
                                   __ATOMIC_RELAXED, __HIP_MEMORY_SCOPE_AGENT);
            }

            const float4 sp = spos[fi];
            if (m < MM - 1) {
#pragma unroll
                for (int k = 0; k < 16; k++) {
                    float nd = dist2_exact(px[k], py[k], pz[k], sp.x, sp.y, sp.z);
                    d[k] = fminf(d[k], nd);
                }
                float t1[8], t2[4];
#pragma unroll
                for (int k = 0; k < 8; k++) t1[k] = fmaxf(d[2 * k], d[2 * k + 1]);
#pragma unroll
                for (int k = 0; k < 4; k++) t2[k] = fmaxf(t1[2 * k], t1[2 * k + 1]);
                bv = fmaxf(fmaxf(t2[0], t2[1]), fmaxf(t2[2], t2[3]));
            }
        }

        __syncthreads();
        for (int i = tid; i < MM; i += 256) {
            float4 sp = spos[shist[i]];
            size_t o = (size_t)b * MM + i;
            pos_s[o * 3 + 0] = sp.x;
            pos_s[o * 3 + 1] = sp.y;
            pos_s[o * 3 + 2] = sp.z;
        }
        return;
    }

    // ===================== CONSUMER: radius + MLP =====================
    {
        const float4* s2 = (const float4*)W2;
        float4*       d2 = (float4*)sW2;
        for (int i = tid; i < 64 * 64 / 4; i += 256) d2[i] = s2[i];
        const float4* s3 = (const float4*)W3;
        float4*       d3 = (float4*)sW3;
        for (int i = tid; i < 64 * 128 / 4; i += 256) d3[i] = s3[i];
    }
    float w1c[6];
#pragma unroll
    for (int c = 0; c < 6; c++) w1c[c] = W1[c * 64 + lane];
    const float bb1  = b1[lane];
    const float bb2  = b2[lane];
    const float bb3a = b3[lane];
    const float bb3b = b3[64 + lane];
    __syncthreads();

    const int W = (blockIdx.x - BB) * 4 + wave;    // 0..991

    // collect this wave's queries and sort by m = q & 1023 (availability order)
    int myq[9]; int nq = 0;
#pragma unroll
    for (int k = 0; k < 9; k++) {
        int q = W + NWRK * k;
        if (q < BB * MM) myq[nq++] = q;
    }
    for (int i = 1; i < nq; i++) {                 // insertion sort (<=9 elems)
        int v = myq[i]; int j = i - 1;
        while (j >= 0 && (myq[j] & 1023) > (v & 1023)) { myq[j + 1] = myq[j]; j--; }
        myq[j + 1] = v;
    }

    for (int i = 0; i < nq; i++) {
        const int q = myq[i];

        // ---- wait for this single query (one address, deep sleep) ----
        unsigned v = 0u;
        int guard = 0;
        for (;;) {
            v = __hip_atomic_load(&gsel[q], __ATOMIC_RELAXED,
                                  __HIP_MEMORY_SCOPE_AGENT);
            if (v >= 1u && v <= (unsigned)NN) break;
            if (++guard > 6000) break;             // ~20ms bound: fail loudly
            __builtin_amdgcn_s_sleep(127);         // ~8128 cyc =~ 3.4us idle
        }
        if (v == 0u || v > (unsigned)NN) continue;

        // ---------- process query q (r12 body; qpos from pos[]) ----------
        const int b  = q >> 10;
        const int fi = (int)v - 1;
        const float qx = pos[((size_t)b * NN + fi) * 3 + 0];
        const float qy = pos[((size_t)b * NN + fi) * 3 + 1];
        const float qz = pos[((size_t)b * NN + fi) * 3 + 2];

        // radius scan: first-16 by index within RSQ (identical semantics)
        if (lane < 16) nslot[wave][lane] = 0;
        const float* pb = pos + (size_t)b * NN * 3;
        int cnt = 0;
        for (int c = 0; c < NN / 64; c++) {
            int p = c * 64 + lane;
            float px = pb[p * 3 + 0], py = pb[p * 3 + 1], pz = pb[p * 3 + 2];
            float d2 = dist2_exact(qx, qy, qz, px, py, pz);
            bool val = (d2 <= RSQ);
            unsigned long long msk = __ballot(val);
            if (val) {
                int rank = __popcll(msk & ((1ull << lane) - 1ull));
                int slot = cnt + rank;
                if (slot < KK) nslot[wave][slot] = p;
            }
            cnt += __popcll(msk);
            if (cnt >= KK) break;
        }
        const int cnt16 = min(cnt, KK);

        const int4 n0 = *(const int4*)&nslot[wave][0];
        const int4 n1 = *(const int4*)&nslot[wave][4];
        const int4 n2 = *(const int4*)&nslot[wave][8];
        const int4 n3 = *(const int4*)&nslot[wave][12];
        const int nidx[16] = { n0.x, n0.y, n0.z, n0.w, n1.x, n1.y, n1.z, n1.w,
                               n2.x, n2.y, n2.z, n2.w, n3.x, n3.y, n3.z, n3.w };

        // layer 1
        float h[17];
        unsigned vmask = 1u << 16;
#pragma unroll
        for (int e = 0; e < 16; e++) {
            const int p = (e < cnt16) ? nidx[e] : 0;
            const int g = b * NN + p;
            if ((e < cnt16) && (g != q)) vmask |= (1u << e);
            const float f0 = x[(size_t)g * 3 + 0];
            const float f1 = x[(size_t)g * 3 + 1];
            const float f2 = x[(size_t)g * 3 + 2];
            const float f3 = pos[(size_t)g * 3 + 0] - qx;
            const float f4 = pos[(size_t)g * 3 + 1] - qy;
            const float f5 = pos[(size_t)g * 3 + 2] - qz;
            float t = bb1 + f0 * w1c[0] + f1 * w1c[1] + f2 * w1c[2]
                          + f3 * w1c[3] + f4 * w1c[4] + f5 * w1c[5];
            h[e] = fmaxf(t, 0.0f);
        }
        {   // added self-loop (PyG numeric quirk)
            const int g = q;
            const float f0 = x[(size_t)g * 3 + 0];
            const float f1 = x[(size_t)g * 3 + 1];
            const float f2 = x[(size_t)g * 3 + 2];
            const float f3 = pos[(size_t)g * 3 + 0] - qx;
            const float f4 = pos[(size_t)g * 3 + 1] - qy;
            const float f5 = pos[(size_t)g * 3 + 2] - qz;
            float t = bb1 + f0 * w1c[0] + f1 * w1c[1] + f2 * w1c[2]
                          + f3 * w1c[3] + f4 * w1c[4] + f5 * w1c[5];
            h[16] = fmaxf(t, 0.0f);
        }

        // layer 2
        float acc[17];
#pragma unroll
        for (int e = 0; e < 17; e++) acc[e] = bb2;
#pragma unroll 2
        for (int j = 0; j < 64; j++) {
            const float wj = sW2[j * 64 + lane];
#pragma unroll
            for (int e = 0; e < 17; e++) {
                const float hj = readlane_f(h[e], j);
                acc[e] = __builtin_fmaf(hj, wj, acc[e]);
            }
        }
#pragma unroll
        for (int e = 0; e < 17; e++) h[e] = fmaxf(acc[e], 0.0f);

        // layer 3
        float a0[17], a1[17];
#pragma unroll
        for (int e = 0; e < 17; e++) { a0[e] = bb3a; a1[e] = bb3b; }
#pragma unroll 2
        for (int j = 0; j < 64; j++) {
            const float wa = sW3[j * 128 + lane];
            const float wb = sW3[j * 128 + 64 + lane];
#pragma unroll
            for (int e = 0; e < 17; e++) {
                const float hj = readlane_f(h[e], j);
                a0[e] = __builtin_fmaf(hj, wa, a0[e]);
                a1[e] = __builtin_fmaf(hj, wb, a1[e]);
            }
        }

        // masked max
        float m0 = -INFINITY, m1 = -INFINITY;
#pragma unroll
        for (int e = 0; e < 17; e++) {
            const bool vv = (vmask >> e) & 1u;
            m0 = vv ? fmaxf(m0, a0[e]) : m0;
            m1 = vv ? fmaxf(m1, a1[e]) : m1;
        }
        out[(size_t)q * COUT + lane]      = m0;
        out[(size_t)q * COUT + 64 + lane] = m1;
    }
}

// ---------------------------------------------------------------------------
extern "C" void kernel_launch(void* const* d_in, const int* in_sizes, int n_in,
                              void* d_out, int out_size, void* d_ws, size_t ws_size,
                              hipStream_t stream) {
    const float* x   = (const float*)d_in[0];
    const float* pos = (const float*)d_in[1];
    // d_in[2] = batch (unused: layout is implicit)
    const float* W1 = (const float*)d_in[3];
    const float* b1 = (const float*)d_in[4];
    const float* W2 = (const float*)d_in[5];
    const float* b2 = (const float*)d_in[6];
    const float* W3 = (const float*)d_in[7];
    const float* b3 = (const float*)d_in[8];

    float* outF    = (float*)d_out;
    float* out     = outF;                                  // [B*M, 128]
    float* pos_s   = outF + (size_t)BB * MM * COUT;         // [B*M, 3]
    float* batch_s = pos_s + (size_t)BB * MM * 3;           // [B*M]

    unsigned* gsel = (unsigned*)d_ws;                       // [B*M] selection index+1

    hipMemsetAsync(gsel, 0, (size_t)BB * MM * sizeof(unsigned), stream);

    fused_kernel<<<256, 256, 0, stream>>>(x, pos, W1, b1, W2, b2, W3, b3,
                                          gsel, out, pos_s, batch_s);
}